// Round 1
// baseline (302.640 us; speedup 1.0000x reference)
//
#include <hip/hip_runtime.h>

#define CLS 6

constexpr int HIST_BLOCKS  = 2048;
constexpr int HIST_THREADS = 256;

__global__ __launch_bounds__(HIST_THREADS, 8)
void cm_hist_kernel(const float* __restrict__ inputs,
                    const int*   __restrict__ targets,
                    const float* __restrict__ wts,
                    unsigned int* __restrict__ cm,
                    long long n_rows) {
    __shared__ unsigned int cm_s[CLS * CLS];
    const int tid = threadIdx.x;
    if (tid < CLS * CLS) cm_s[tid] = 0u;
    __syncthreads();

    const float w0 = wts[0], w1 = wts[1], w2 = wts[2];
    const float w3 = wts[3], w4 = wts[4], w5 = wts[5];

    const float4* __restrict__ in4 = (const float4*)inputs;
    const int2*   __restrict__ tg2 = (const int2*)targets;

    const long long n_pairs = n_rows >> 1;
    const long long stride  = (long long)gridDim.x * blockDim.x;

    for (long long p = (long long)blockIdx.x * blockDim.x + tid;
         p < n_pairs; p += stride) {
        // rows 2p, 2p+1 : 48 bytes = 3 aligned float4
        float4 a = in4[3 * p + 0];
        float4 b = in4[3 * p + 1];
        float4 c = in4[3 * p + 2];
        int2   t = tg2[p];

        // row A = a.x a.y a.z a.w b.x b.y
        {
            float v0 = a.x * w0, v1 = a.y * w1, v2 = a.z * w2;
            float v3 = a.w * w3, v4 = b.x * w4, v5 = b.y * w5;
            int   pr = 0; float m = v0;
            if (v1 > m) { m = v1; pr = 1; }
            if (v2 > m) { m = v2; pr = 2; }
            if (v3 > m) { m = v3; pr = 3; }
            if (v4 > m) { m = v4; pr = 4; }
            if (v5 > m) { m = v5; pr = 5; }
            atomicAdd(&cm_s[pr * CLS + t.x], 1u);
        }
        // row B = b.z b.w c.x c.y c.z c.w
        {
            float v0 = b.z * w0, v1 = b.w * w1, v2 = c.x * w2;
            float v3 = c.y * w3, v4 = c.z * w4, v5 = c.w * w5;
            int   pr = 0; float m = v0;
            if (v1 > m) { m = v1; pr = 1; }
            if (v2 > m) { m = v2; pr = 2; }
            if (v3 > m) { m = v3; pr = 3; }
            if (v4 > m) { m = v4; pr = 4; }
            if (v5 > m) { m = v5; pr = 5; }
            atomicAdd(&cm_s[pr * CLS + t.y], 1u);
        }
    }

    // odd tail row (N is even here, but stay correct in general)
    if (blockIdx.x == 0 && tid == 0 && (n_rows & 1)) {
        long long r = n_rows - 1;
        int   pr = 0;
        float m  = inputs[r * CLS + 0] * w0;
        float v;
        v = inputs[r * CLS + 1] * w1; if (v > m) { m = v; pr = 1; }
        v = inputs[r * CLS + 2] * w2; if (v > m) { m = v; pr = 2; }
        v = inputs[r * CLS + 3] * w3; if (v > m) { m = v; pr = 3; }
        v = inputs[r * CLS + 4] * w4; if (v > m) { m = v; pr = 4; }
        v = inputs[r * CLS + 5] * w5; if (v > m) { m = v; pr = 5; }
        atomicAdd(&cm_s[pr * CLS + targets[r]], 1u);
    }

    __syncthreads();
    if (tid < CLS * CLS) {
        unsigned int v = cm_s[tid];
        if (v) atomicAdd(&cm[tid], v);   // device-scope by default
    }
}

__global__ void macro_score_kernel(const unsigned int* __restrict__ cm,
                                   const float* __restrict__ wts,
                                   float* __restrict__ out) {
    if (threadIdx.x == 0) {
        float c[CLS * CLS];
        #pragma unroll
        for (int i = 0; i < CLS * CLS; ++i) c[i] = (float)cm[i];
        float f1sum = 0.0f;
        #pragma unroll
        for (int i = 0; i < CLS; ++i) {
            float col = 0.0f, row = 0.0f;
            #pragma unroll
            for (int j = 0; j < CLS; ++j) {
                col += c[j * CLS + i];   // cm.sum(axis=0)[i]  (over preds)
                row += c[i * CLS + j];   // cm.sum(axis=1)[i]  (over targets)
            }
            float d  = c[i * CLS + i];
            float pr = d / col;
            float rc = d / row;
            f1sum += 2.0f * pr * rc / (pr + rc);
        }
        out[0] = -(f1sum / (float)CLS);
    }
    if (threadIdx.x < CLS) out[1 + threadIdx.x] = wts[threadIdx.x];
}

extern "C" void kernel_launch(void* const* d_in, const int* in_sizes, int n_in,
                              void* d_out, int out_size, void* d_ws, size_t ws_size,
                              hipStream_t stream) {
    const float* inputs  = (const float*)d_in[0];
    const int*   targets = (const int*)d_in[1];
    const float* wts     = (const float*)d_in[2];
    float*       out     = (float*)d_out;
    unsigned int* cm     = (unsigned int*)d_ws;

    const long long n_rows = (long long)in_sizes[0] / CLS;

    hipMemsetAsync(cm, 0, CLS * CLS * sizeof(unsigned int), stream);
    cm_hist_kernel<<<HIST_BLOCKS, HIST_THREADS, 0, stream>>>(inputs, targets, wts, cm, n_rows);
    macro_score_kernel<<<1, 64, 0, stream>>>(cm, wts, out);
}